// Round 1
// baseline (1108.273 us; speedup 1.0000x reference)
//
#include <hip/hip_runtime.h>

#define PARTS 16
#define NB 128
#define CH 256
#define SL 64
#define HIDN 64

typedef unsigned short u16;
typedef unsigned short ushort8 __attribute__((ext_vector_type(8)));
typedef unsigned short ushort4v __attribute__((ext_vector_type(4)));

__device__ __forceinline__ float bf2f(u16 u) {
  union { unsigned u; float f; } t; t.u = ((unsigned)u) << 16; return t.f;
}
__device__ __forceinline__ u16 f2bf(float f) {
  union { float f; unsigned u; } t; t.f = f;
  unsigned u = t.u;
  u += 0x7FFFu + ((u >> 16) & 1u);
  return (u16)(u >> 16);
}

// LDS row layouts: rows of 72 bf16 (144 B, 16B-aligned), payload at s-index 0..63,
// trailing pad 64..71 zeroed. Buffer has 8 leading zero elements so s-index -1/-2
// (and the aligned window start s_base-8) stay in-bounds and read zero.
#define XROW 72
#define HROW 72

__global__ __launch_bounds__(256, 2) void tfa_kernel(
    const float* __restrict__ x,
    const float* __restrict__ w1a,
    const float* __restrict__ w1b,
    const float* __restrict__ w3a,
    const float* __restrict__ w3b,
    float* __restrict__ out)
{
  __shared__ __attribute__((aligned(16))) u16 x_s[8 + CH * XROW];    // 36,880 B
  __shared__ __attribute__((aligned(16))) u16 h1_s[8 + HIDN * HROW]; //  9,232 B
  __shared__ __attribute__((aligned(16))) u16 h3_s[8 + HIDN * HROW]; //  9,232 B

  const int tid = threadIdx.x;
  const int bid = blockIdx.x;      // p*NB + n
  const int p = bid >> 7;          // NB = 128

  // ---- zero pads (disjoint from value slots; one barrier covers both) ----
  {
    const ushort8 z = {0, 0, 0, 0, 0, 0, 0, 0};
    for (int i = tid; i < 257; i += 256) {
      u16* dst = (i == 0) ? &x_s[0] : &x_s[8 + (i - 1) * XROW + 64];
      *(ushort8*)dst = z;
    }
    if (tid < 65) {
      u16* d1 = (tid == 0) ? &h1_s[0] : &h1_s[8 + (tid - 1) * HROW + 64];
      *(ushort8*)d1 = z;
      u16* d3 = (tid == 0) ? &h3_s[0] : &h3_s[8 + (tid - 1) * HROW + 64];
      *(ushort8*)d3 = z;
    }
  }

  // ---- stage x -> LDS (bf16), coalesced float4 ----
  const float* xblk = x + (size_t)bid * (CH * SL);
  #pragma unroll
  for (int j = 0; j < 16; ++j) {
    const int g = tid + 256 * j;          // float4 index in [0,4096)
    const float4 v = ((const float4*)xblk)[g];
    const int c = g >> 4, s4 = g & 15;
    ushort4v o;
    o[0] = f2bf(v.x); o[1] = f2bf(v.y); o[2] = f2bf(v.z); o[3] = f2bf(v.w);
    *(ushort4v*)&x_s[8 + c * XROW + s4 * 4] = o;
  }
  __syncthreads();

  // ---- phase A: conv1 (both branches) + LeakyReLU -> h1_s/h3_s ----
  // thread t: h = t>>2 (0..63), sg = t&3, computes 16 s-positions per branch
  {
    const int h = tid >> 2;
    const int sg = tid & 3;
    const int sb = sg << 4;               // s_base
    float acc1[16], acc3[16];
    #pragma unroll
    for (int i = 0; i < 16; ++i) { acc1[i] = 0.f; acc3[i] = 0.f; }

    const float* w1a_p = w1a + ((size_t)p * HIDN + h) * (CH * 3);
    const float* w3a_p = w3a + ((size_t)p * HIDN + h) * (CH * 3);

    for (int c4 = 0; c4 < CH; c4 += 4) {
      // 12 consecutive f32 weights per branch (16B-aligned at c4%4==0)
      const float4 a0v = *(const float4*)&w1a_p[c4 * 3];
      const float4 a1v = *(const float4*)&w1a_p[c4 * 3 + 4];
      const float4 a2v = *(const float4*)&w1a_p[c4 * 3 + 8];
      const float4 b0v = *(const float4*)&w3a_p[c4 * 3];
      const float4 b1v = *(const float4*)&w3a_p[c4 * 3 + 4];
      const float4 b2v = *(const float4*)&w3a_p[c4 * 3 + 8];
      float wa[12], wb[12];
      wa[0]=a0v.x; wa[1]=a0v.y; wa[2]=a0v.z; wa[3]=a0v.w;
      wa[4]=a1v.x; wa[5]=a1v.y; wa[6]=a1v.z; wa[7]=a1v.w;
      wa[8]=a2v.x; wa[9]=a2v.y; wa[10]=a2v.z; wa[11]=a2v.w;
      wb[0]=b0v.x; wb[1]=b0v.y; wb[2]=b0v.z; wb[3]=b0v.w;
      wb[4]=b1v.x; wb[5]=b1v.y; wb[6]=b1v.z; wb[7]=b1v.w;
      wb[8]=b2v.x; wb[9]=b2v.y; wb[10]=b2v.z; wb[11]=b2v.w;

      #pragma unroll
      for (int cc = 0; cc < 4; ++cc) {
        const int c = c4 + cc;
        // aligned 16B window reads: s-index sb-8 .. sb+23
        const ushort8 w0v = *(const ushort8*)&x_s[c * XROW + sb];       // sb-8..sb-1
        const ushort8 w1v = *(const ushort8*)&x_s[c * XROW + sb + 8];   // sb..sb+7
        const ushort8 w2v = *(const ushort8*)&x_s[c * XROW + sb + 16];  // sb+8..sb+15
        const ushort8 w3v = *(const ushort8*)&x_s[c * XROW + sb + 24];  // sb+16..sb+23
        float xf[19];                    // xf[d] = x[c][sb-1+d]
        xf[0] = bf2f(w0v[7]);
        #pragma unroll
        for (int d = 0; d < 8; ++d) xf[1 + d] = bf2f(w1v[d]);
        #pragma unroll
        for (int d = 0; d < 8; ++d) xf[9 + d] = bf2f(w2v[d]);
        xf[17] = bf2f(w3v[0]);
        xf[18] = bf2f(w3v[1]);

        const float a0 = wa[cc * 3], a1 = wa[cc * 3 + 1], a2 = wa[cc * 3 + 2];
        const float b0 = wb[cc * 3], b1 = wb[cc * 3 + 1], b2 = wb[cc * 3 + 2];
        #pragma unroll
        for (int i = 0; i < 16; ++i) {
          const float xm = xf[i], x0 = xf[i + 1], xp = xf[i + 2];
          acc1[i] = fmaf(a0, xm, fmaf(a1, x0, fmaf(a2, xp, acc1[i])));
          acc3[i] = fmaf(b0, xm, fmaf(b1, x0, fmaf(b2, xp, acc3[i])));
        }
      }
    }

    // LeakyReLU + store hidden (bf16), two 16B writes per buffer
    ushort8 o1a, o1b, o3a, o3b;
    #pragma unroll
    for (int i = 0; i < 8; ++i) {
      float v1 = acc1[i];     v1 = v1 >= 0.f ? v1 : 0.01f * v1;
      float v3 = acc3[i];     v3 = v3 >= 0.f ? v3 : 0.01f * v3;
      o1a[i] = f2bf(v1); o3a[i] = f2bf(v3);
      float u1 = acc1[i + 8]; u1 = u1 >= 0.f ? u1 : 0.01f * u1;
      float u3 = acc3[i + 8]; u3 = u3 >= 0.f ? u3 : 0.01f * u3;
      o1b[i] = f2bf(u1); o3b[i] = f2bf(u3);
    }
    *(ushort8*)&h1_s[8 + h * HROW + sb]     = o1a;
    *(ushort8*)&h1_s[8 + h * HROW + sb + 8] = o1b;
    *(ushort8*)&h3_s[8 + h * HROW + sb]     = o3a;
    *(ushort8*)&h3_s[8 + h * HROW + sb + 8] = o3b;
  }
  __syncthreads();

  // ---- phase B: conv2 (both branches) + sigmoid gates + pools + max over s ----
  // lane = s; each wave owns 64 channels, processed 4 at a time
  {
    const int lane = tid & 63;
    const int wid = __builtin_amdgcn_readfirstlane(tid >> 6);  // wave-uniform
    const int s = lane;
    const float* w1b_p = w1b + (size_t)p * (CH * HIDN);
    const float* w3b_p = w3b + (size_t)p * (CH * HIDN * 3);
    float* outp = out + (size_t)bid * CH;

    for (int q = 0; q < 16; ++q) {
      const int c0 = wid * 64 + q * 4;
      float l1[4] = {0.f, 0.f, 0.f, 0.f};
      float l3[4] = {0.f, 0.f, 0.f, 0.f};

      for (int h4 = 0; h4 < HIDN; h4 += 4) {
        float h1v[4], h3a[4], h3b[4], h3c[4];
        #pragma unroll
        for (int u = 0; u < 4; ++u) {
          const int hh = h4 + u;
          h1v[u] = bf2f(h1_s[8 + hh * HROW + s]);
          h3a[u] = bf2f(h3_s[7 + hh * HROW + s]);   // s-1 (zero-padded)
          h3b[u] = bf2f(h3_s[8 + hh * HROW + s]);   // s
          h3c[u] = bf2f(h3_s[9 + hh * HROW + s]);   // s+1 (zero-padded)
        }
        #pragma unroll
        for (int j = 0; j < 4; ++j) {
          const int c = c0 + j;
          const float4 wv  = *(const float4*)&w1b_p[c * HIDN + h4];
          const float* w3  = &w3b_p[(size_t)(c * HIDN + h4) * 3];
          const float4 w30 = *(const float4*)w3;
          const float4 w31 = *(const float4*)(w3 + 4);
          const float4 w32 = *(const float4*)(w3 + 8);
          float ww[12];
          ww[0]=w30.x; ww[1]=w30.y; ww[2]=w30.z; ww[3]=w30.w;
          ww[4]=w31.x; ww[5]=w31.y; ww[6]=w31.z; ww[7]=w31.w;
          ww[8]=w32.x; ww[9]=w32.y; ww[10]=w32.z; ww[11]=w32.w;
          l1[j] = fmaf(wv.x, h1v[0], fmaf(wv.y, h1v[1],
                  fmaf(wv.z, h1v[2], fmaf(wv.w, h1v[3], l1[j]))));
          #pragma unroll
          for (int u = 0; u < 4; ++u) {
            l3[j] = fmaf(ww[u * 3], h3a[u],
                    fmaf(ww[u * 3 + 1], h3b[u],
                    fmaf(ww[u * 3 + 2], h3c[u], l3[j])));
          }
        }
      }

      #pragma unroll
      for (int j = 0; j < 4; ++j) {
        const int c = c0 + j;
        const u16* xr = &x_s[8 + c * XROW];
        const float xm2 = bf2f(xr[s - 2]);   // zero pads in LDS
        const float xm1 = bf2f(xr[s - 1]);
        const float x0  = bf2f(xr[s]);
        const float xp1 = bf2f(xr[s + 1]);
        const float xp2 = bf2f(xr[s + 2]);
        const float NI = -INFINITY;
        // max pools: exclude out-of-range (pad) via -inf mask
        const float mx3 = fmaxf(x0, fmaxf(s >= 1 ? xm1 : NI, s <= 62 ? xp1 : NI));
        const float mx5 = fmaxf(mx3, fmaxf(s >= 2 ? xm2 : NI, s <= 61 ? xp2 : NI));
        // avg pools: count_include_pad=True -> zeros counted, fixed divisor
        const float av3 = (xm1 + x0 + xp1) * (1.f / 3.f);
        const float av5 = (xm2 + xm1 + x0 + xp1 + xp2) * 0.2f;
        const float sg1 = 1.f / (1.f + __expf(-l1[j]));
        const float sg3 = 1.f / (1.f + __expf(-l3[j]));
        float feat = (av3 + mx3) * sg1 + (av5 + mx5) * sg3;
        // max over s (64 lanes)
        #pragma unroll
        for (int off = 32; off >= 1; off >>= 1)
          feat = fmaxf(feat, __shfl_xor(feat, off));
        if (lane == 0) outp[c] = feat;
      }
    }
  }
}

extern "C" void kernel_launch(void* const* d_in, const int* in_sizes, int n_in,
                              void* d_out, int out_size, void* d_ws, size_t ws_size,
                              hipStream_t stream) {
  (void)in_sizes; (void)n_in; (void)out_size; (void)d_ws; (void)ws_size;
  const float* x   = (const float*)d_in[0];
  const float* w1a = (const float*)d_in[1];
  const float* w1b = (const float*)d_in[2];
  const float* w3a = (const float*)d_in[3];
  const float* w3b = (const float*)d_in[4];
  float* out = (float*)d_out;
  tfa_kernel<<<PARTS * NB, 256, 0, stream>>>(x, w1a, w1b, w3a, w3b, out);
}

// Round 2
// 143.044 us; speedup vs baseline: 7.7478x; 7.7478x over previous
//
#include <hip/hip_runtime.h>

#define PARTS 16
#define NB 128
#define CH 256
#define SL 64
#define HIDN 64

typedef unsigned short u16;
typedef unsigned short ushort8 __attribute__((ext_vector_type(8)));
typedef unsigned short ushort4v __attribute__((ext_vector_type(4)));
typedef __attribute__((ext_vector_type(8))) short short8v;
typedef __attribute__((ext_vector_type(4))) short short4v;
typedef __attribute__((ext_vector_type(4))) float f32x4;

__device__ __forceinline__ float bf2f(u16 u) {
  union { unsigned u; float f; } t; t.u = ((unsigned)u) << 16; return t.f;
}
__device__ __forceinline__ u16 f2bf(float f) {
  union { float f; unsigned u; } t; t.f = f;
  unsigned u = t.u;
  u += 0x7FFFu + ((u >> 16) & 1u);
  return (u16)(u >> 16);
}

// ===================== weight conversion prepass =====================
// out[p][t][x] = bf16(in[p][x][t]);  NX = 16384 fixed, NT = 3 or 1.
// Covers: w1a[p][h][c][t]->[p][t][h][c], w3a same, w1b (NT=1) passthrough,
//         w3b[p][c][h][t]->[p][t][c][h].
__global__ void cvt_tap(const float* __restrict__ in, u16* __restrict__ out, int NT) {
  const int i = blockIdx.x * 256 + threadIdx.x;   // p*16384 + x, exact grid
  const int p = i >> 14, xid = i & 16383;
  const float* src = in + (size_t)i * NT;
  for (int t = 0; t < NT; ++t)
    out[(size_t)(p * NT + t) * 16384 + xid] = f2bf(src[t]);
}

// ===================== MFMA main kernel =====================
// LDS layouts (bf16, XOR-swizzled in 16B chunks):
//  XT[r][c]: r = s+2, rows 0..67 (s=-2..65), 256 cols. pad rows 0,1,66,67 = 0.
//  HT[r][h]: r = s+1, rows 0..65 (s=-1..64), 64 cols.  pad rows 0,65 = 0.
#define XROWS 68
#define HROWS 66

__device__ __forceinline__ int xsw(int r, int c) { return (r * 256 + c) ^ ((r & 7) << 3); }
__device__ __forceinline__ int hsw(int r, int c) { return (r * 64 + c) ^ ((r & 7) << 3); }

__global__ __launch_bounds__(256, 3) void tfa_mfma(
    const float* __restrict__ x,
    const u16* __restrict__ wsb,
    float* __restrict__ out)
{
  const u16* W1A = wsb;                 // [p][t][h][c]  786432
  const u16* W3A = wsb + 786432;        // [p][t][h][c]  786432
  const u16* W1B = wsb + 1572864;       // [p][c][h]     262144
  const u16* W3B = wsb + 1835008;       // [p][t][c][h]  786432

  __shared__ __attribute__((aligned(16))) u16 xt[XROWS * 256];   // 34816 B
  __shared__ __attribute__((aligned(16))) u16 ht1[HROWS * 64];   //  8448 B
  __shared__ __attribute__((aligned(16))) u16 ht3[HROWS * 64];   //  8448 B

  const int tid = threadIdx.x;
  const int bid = blockIdx.x;          // p*NB + n
  const int p = bid >> 7;
  const int lane = tid & 63;
  const int w = tid >> 6;              // wave id 0..3

  // ---- zero the pad rows ----
  if (tid < 128) {
    const int rr4 = (tid >> 5);
    const int r = (rr4 == 0) ? 0 : (rr4 == 1) ? 1 : (rr4 == 2) ? 66 : 67;
    const int c = (tid & 31) * 8;
    *(ushort8*)&xt[xsw(r, c)] = (ushort8)0;
  } else if (tid < 160) {
    const int t2 = tid - 128;          // 0..31: bit4=buffer, bit3=row, bits0-2=col chunk
    const int r = (t2 & 8) ? 65 : 0;
    const int c = (t2 & 7) * 8;
    u16* b = (t2 & 16) ? ht3 : ht1;
    *(ushort8*)&b[hsw(r, c)] = (ushort8)0;
  }

  // ---- stage x -> XT (transposed, bf16, swizzled) ----
  // lane = s; wave w covers c in [w*64, w*64+64); scalar loads coalesced across lanes
  {
    const float* xb = x + (size_t)bid * (CH * SL);
    const int s = lane;
    const int r = s + 2;
    #pragma unroll
    for (int j = 0; j < 8; ++j) {
      const int c0 = w * 64 + j * 8;
      ushort8 ov;
      #pragma unroll
      for (int k = 0; k < 8; ++k) ov[k] = f2bf(xb[(c0 + k) * 64 + s]);
      *(ushort8*)&xt[xsw(r, c0)] = ov;
    }
  }
  __syncthreads();

  // ---- phase A: conv1 both branches via MFMA, tap-GEMMs with shifted B rows ----
  // wave w owns h in [w*16, w*16+16); M=16h x N=64s x K=256c per tap
  {
    const int hm = lane & 15;          // A-frag m index
    const int kg = lane >> 4;          // k-group
    const int h = w * 16 + hm;
    f32x4 acc1[4], acc3[4];
    #pragma unroll
    for (int nt = 0; nt < 4; ++nt) { acc1[nt] = (f32x4)0.f; acc3[nt] = (f32x4)0.f; }

    #pragma unroll 2
    for (int ks = 0; ks < 8; ++ks) {
      const int kc = ks * 32 + kg * 8;
      short8v a1[3], a3[3];
      #pragma unroll
      for (int t = 0; t < 3; ++t) {
        a1[t] = *(const short8v*)&W1A[(size_t)((p * 3 + t) * 64 + h) * 256 + kc];
        a3[t] = *(const short8v*)&W3A[(size_t)((p * 3 + t) * 64 + h) * 256 + kc];
      }
      #pragma unroll
      for (int nt = 0; nt < 4; ++nt) {
        const int s = nt * 16 + hm;    // B-frag n index = lane&15
        #pragma unroll
        for (int t = 0; t < 3; ++t) {
          const int r = s + t + 1;     // s + (t-1) + 2
          const short8v b = *(const short8v*)&xt[xsw(r, kc)];
          acc1[nt] = __builtin_amdgcn_mfma_f32_16x16x32_bf16(a1[t], b, acc1[nt], 0, 0, 0);
          acc3[nt] = __builtin_amdgcn_mfma_f32_16x16x32_bf16(a3[t], b, acc3[nt], 0, 0, 0);
        }
      }
    }

    // epilogue: LeakyReLU -> bf16 -> HT[s][h] (D: col=lane&15 -> s, row=(lane>>4)*4+q -> h)
    const int hc = w * 16 + kg * 4;
    #pragma unroll
    for (int nt = 0; nt < 4; ++nt) {
      const int s = nt * 16 + hm;
      const int r = s + 1;
      ushort4v o1, o3;
      #pragma unroll
      for (int q = 0; q < 4; ++q) {
        float v1 = acc1[nt][q]; v1 = v1 >= 0.f ? v1 : 0.01f * v1;
        float v3 = acc3[nt][q]; v3 = v3 >= 0.f ? v3 : 0.01f * v3;
        o1[q] = f2bf(v1); o3[q] = f2bf(v3);
      }
      *(ushort4v*)&ht1[hsw(r, hc)] = o1;
      *(ushort4v*)&ht3[hsw(r, hc)] = o3;
    }
  }
  __syncthreads();

  // ---- phase B: conv2 both branches via MFMA + gates + pools + max over s ----
  // wave w owns c in [w*64, w*64+64): 4 m-tiles x 4 n-tiles
  {
    const int cm = lane & 15;
    const int kg = lane >> 4;
    f32x4 acc[4][4];
    #pragma unroll
    for (int mt = 0; mt < 4; ++mt)
      #pragma unroll
      for (int nt = 0; nt < 4; ++nt) acc[mt][nt] = (f32x4)0.f;

    // branch 1: K=64h, k1 conv (no shift)
    #pragma unroll
    for (int ks = 0; ks < 2; ++ks) {
      const int kh = ks * 32 + kg * 8;
      short8v a[4];
      #pragma unroll
      for (int mt = 0; mt < 4; ++mt) {
        const int c = w * 64 + mt * 16 + cm;
        a[mt] = *(const short8v*)&W1B[((size_t)p * 256 + c) * 64 + kh];
      }
      #pragma unroll
      for (int nt = 0; nt < 4; ++nt) {
        const int s = nt * 16 + cm;
        const short8v b = *(const short8v*)&ht1[hsw(s + 1, kh)];
        #pragma unroll
        for (int mt = 0; mt < 4; ++mt)
          acc[mt][nt] = __builtin_amdgcn_mfma_f32_16x16x32_bf16(a[mt], b, acc[mt][nt], 0, 0, 0);
      }
    }

    // stash gates g1 = sigmoid(L1) as packed bf16 pairs (32 regs)
    unsigned g1p[4][4][2];
    #pragma unroll
    for (int mt = 0; mt < 4; ++mt)
      #pragma unroll
      for (int nt = 0; nt < 4; ++nt) {
        #pragma unroll
        for (int j = 0; j < 2; ++j) {
          const float ga = 1.f / (1.f + __expf(-acc[mt][nt][2 * j]));
          const float gb = 1.f / (1.f + __expf(-acc[mt][nt][2 * j + 1]));
          g1p[mt][nt][j] = (unsigned)f2bf(ga) | ((unsigned)f2bf(gb) << 16);
        }
        acc[mt][nt] = (f32x4)0.f;      // reuse for branch 3
      }

    // branch 3: 3 tap-GEMMs, K=64h each, B rows shifted
    #pragma unroll
    for (int ks = 0; ks < 2; ++ks) {
      const int kh = ks * 32 + kg * 8;
      #pragma unroll
      for (int t = 0; t < 3; ++t) {
        short8v a[4];
        #pragma unroll
        for (int mt = 0; mt < 4; ++mt) {
          const int c = w * 64 + mt * 16 + cm;
          a[mt] = *(const short8v*)&W3B[(size_t)((p * 3 + t) * 256 + c) * 64 + kh];
        }
        #pragma unroll
        for (int nt = 0; nt < 4; ++nt) {
          const int s = nt * 16 + cm;
          const short8v b = *(const short8v*)&ht3[hsw(s + t, kh)];  // s + (t-1) + 1
          #pragma unroll
          for (int mt = 0; mt < 4; ++mt)
            acc[mt][nt] = __builtin_amdgcn_mfma_f32_16x16x32_bf16(a[mt], b, acc[mt][nt], 0, 0, 0);
        }
      }
    }

    // epilogue: pools from XT, gates, fused max over s
    #pragma unroll
    for (int mt = 0; mt < 4; ++mt) {
      const int c4 = w * 64 + mt * 16 + kg * 4;   // D rows: 4 consecutive c
      float fmx0 = -INFINITY, fmx1 = -INFINITY, fmx2 = -INFINITY, fmx3 = -INFINITY;
      #pragma unroll
      for (int nt = 0; nt < 4; ++nt) {
        const int s = nt * 16 + cm;               // D col
        const ushort4v vm2 = *(const ushort4v*)&xt[xsw(s,     c4)];
        const ushort4v vm1 = *(const ushort4v*)&xt[xsw(s + 1, c4)];
        const ushort4v v0  = *(const ushort4v*)&xt[xsw(s + 2, c4)];
        const ushort4v vp1 = *(const ushort4v*)&xt[xsw(s + 3, c4)];
        const ushort4v vp2 = *(const ushort4v*)&xt[xsw(s + 4, c4)];
        const float NI = -INFINITY;
        float ft[4];
        #pragma unroll
        for (int q = 0; q < 4; ++q) {
          const float xm2 = bf2f(vm2[q]), xm1 = bf2f(vm1[q]), x0 = bf2f(v0[q]);
          const float xp1 = bf2f(vp1[q]), xp2 = bf2f(vp2[q]);
          const float mx3 = fmaxf(x0, fmaxf(s >= 1 ? xm1 : NI, s <= 62 ? xp1 : NI));
          const float mx5 = fmaxf(mx3, fmaxf(s >= 2 ? xm2 : NI, s <= 61 ? xp2 : NI));
          const float av3 = (xm1 + x0 + xp1) * (1.f / 3.f);
          const float av5 = (xm2 + xm1 + x0 + xp1 + xp2) * 0.2f;
          const float g1 = bf2f((u16)(g1p[mt][nt][q >> 1] >> ((q & 1) * 16)));
          const float g3 = 1.f / (1.f + __expf(-acc[mt][nt][q]));
          ft[q] = (av3 + mx3) * g1 + (av5 + mx5) * g3;
        }
        fmx0 = fmaxf(fmx0, ft[0]); fmx1 = fmaxf(fmx1, ft[1]);
        fmx2 = fmaxf(fmx2, ft[2]); fmx3 = fmaxf(fmx3, ft[3]);
      }
      // reduce max across the 16 lanes of each row-group (xor bits 0..3)
      #pragma unroll
      for (int off = 1; off < 16; off <<= 1) {
        fmx0 = fmaxf(fmx0, __shfl_xor(fmx0, off));
        fmx1 = fmaxf(fmx1, __shfl_xor(fmx1, off));
        fmx2 = fmaxf(fmx2, __shfl_xor(fmx2, off));
        fmx3 = fmaxf(fmx3, __shfl_xor(fmx3, off));
      }
      if (cm == 0) {
        float4 o; o.x = fmx0; o.y = fmx1; o.z = fmx2; o.w = fmx3;
        *(float4*)&out[(size_t)bid * 256 + c4] = o;
      }
    }
  }
}

// ===================== fallback vector kernel (round-1, correct) =====================
#define XROW 72
#define HROW 72

__global__ __launch_bounds__(256, 2) void tfa_kernel(
    const float* __restrict__ x,
    const float* __restrict__ w1a,
    const float* __restrict__ w1b,
    const float* __restrict__ w3a,
    const float* __restrict__ w3b,
    float* __restrict__ out)
{
  __shared__ __attribute__((aligned(16))) u16 x_s[8 + CH * XROW];
  __shared__ __attribute__((aligned(16))) u16 h1_s[8 + HIDN * HROW];
  __shared__ __attribute__((aligned(16))) u16 h3_s[8 + HIDN * HROW];

  const int tid = threadIdx.x;
  const int bid = blockIdx.x;
  const int p = bid >> 7;

  {
    const ushort8 z = {0, 0, 0, 0, 0, 0, 0, 0};
    for (int i = tid; i < 257; i += 256) {
      u16* dst = (i == 0) ? &x_s[0] : &x_s[8 + (i - 1) * XROW + 64];
      *(ushort8*)dst = z;
    }
    if (tid < 65) {
      u16* d1 = (tid == 0) ? &h1_s[0] : &h1_s[8 + (tid - 1) * HROW + 64];
      *(ushort8*)d1 = z;
      u16* d3 = (tid == 0) ? &h3_s[0] : &h3_s[8 + (tid - 1) * HROW + 64];
      *(ushort8*)d3 = z;
    }
  }

  const float* xblk = x + (size_t)bid * (CH * SL);
  #pragma unroll
  for (int j = 0; j < 16; ++j) {
    const int g = tid + 256 * j;
    const float4 v = ((const float4*)xblk)[g];
    const int c = g >> 4, s4 = g & 15;
    ushort4v o;
    o[0] = f2bf(v.x); o[1] = f2bf(v.y); o[2] = f2bf(v.z); o[3] = f2bf(v.w);
    *(ushort4v*)&x_s[8 + c * XROW + s4 * 4] = o;
  }
  __syncthreads();

  {
    const int h = tid >> 2;
    const int sg = tid & 3;
    const int sb = sg << 4;
    float acc1[16], acc3[16];
    #pragma unroll
    for (int i = 0; i < 16; ++i) { acc1[i] = 0.f; acc3[i] = 0.f; }

    const float* w1a_p = w1a + ((size_t)p * HIDN + h) * (CH * 3);
    const float* w3a_p = w3a + ((size_t)p * HIDN + h) * (CH * 3);

    for (int c4 = 0; c4 < CH; c4 += 4) {
      const float4 a0v = *(const float4*)&w1a_p[c4 * 3];
      const float4 a1v = *(const float4*)&w1a_p[c4 * 3 + 4];
      const float4 a2v = *(const float4*)&w1a_p[c4 * 3 + 8];
      const float4 b0v = *(const float4*)&w3a_p[c4 * 3];
      const float4 b1v = *(const float4*)&w3a_p[c4 * 3 + 4];
      const float4 b2v = *(const float4*)&w3a_p[c4 * 3 + 8];
      float wa[12], wb[12];
      wa[0]=a0v.x; wa[1]=a0v.y; wa[2]=a0v.z; wa[3]=a0v.w;
      wa[4]=a1v.x; wa[5]=a1v.y; wa[6]=a1v.z; wa[7]=a1v.w;
      wa[8]=a2v.x; wa[9]=a2v.y; wa[10]=a2v.z; wa[11]=a2v.w;
      wb[0]=b0v.x; wb[1]=b0v.y; wb[2]=b0v.z; wb[3]=b0v.w;
      wb[4]=b1v.x; wb[5]=b1v.y; wb[6]=b1v.z; wb[7]=b1v.w;
      wb[8]=b2v.x; wb[9]=b2v.y; wb[10]=b2v.z; wb[11]=b2v.w;

      #pragma unroll
      for (int cc = 0; cc < 4; ++cc) {
        const int c = c4 + cc;
        const ushort8 w0v = *(const ushort8*)&x_s[c * XROW + sb];
        const ushort8 w1v = *(const ushort8*)&x_s[c * XROW + sb + 8];
        const ushort8 w2v = *(const ushort8*)&x_s[c * XROW + sb + 16];
        const ushort8 w3v = *(const ushort8*)&x_s[c * XROW + sb + 24];
        float xf[19];
        xf[0] = bf2f(w0v[7]);
        #pragma unroll
        for (int d = 0; d < 8; ++d) xf[1 + d] = bf2f(w1v[d]);
        #pragma unroll
        for (int d = 0; d < 8; ++d) xf[9 + d] = bf2f(w2v[d]);
        xf[17] = bf2f(w3v[0]);
        xf[18] = bf2f(w3v[1]);

        const float a0 = wa[cc * 3], a1 = wa[cc * 3 + 1], a2 = wa[cc * 3 + 2];
        const float b0 = wb[cc * 3], b1 = wb[cc * 3 + 1], b2 = wb[cc * 3 + 2];
        #pragma unroll
        for (int i = 0; i < 16; ++i) {
          const float xm = xf[i], x0 = xf[i + 1], xp = xf[i + 2];
          acc1[i] = fmaf(a0, xm, fmaf(a1, x0, fmaf(a2, xp, acc1[i])));
          acc3[i] = fmaf(b0, xm, fmaf(b1, x0, fmaf(b2, xp, acc3[i])));
        }
      }
    }

    ushort8 o1a, o1b, o3a, o3b;
    #pragma unroll
    for (int i = 0; i < 8; ++i) {
      float v1 = acc1[i];     v1 = v1 >= 0.f ? v1 : 0.01f * v1;
      float v3 = acc3[i];     v3 = v3 >= 0.f ? v3 : 0.01f * v3;
      o1a[i] = f2bf(v1); o3a[i] = f2bf(v3);
      float u1 = acc1[i + 8]; u1 = u1 >= 0.f ? u1 : 0.01f * u1;
      float u3 = acc3[i + 8]; u3 = u3 >= 0.f ? u3 : 0.01f * u3;
      o1b[i] = f2bf(u1); o3b[i] = f2bf(u3);
    }
    *(ushort8*)&h1_s[8 + h * HROW + sb]     = o1a;
    *(ushort8*)&h1_s[8 + h * HROW + sb + 8] = o1b;
    *(ushort8*)&h3_s[8 + h * HROW + sb]     = o3a;
    *(ushort8*)&h3_s[8 + h * HROW + sb + 8] = o3b;
  }
  __syncthreads();

  {
    const int lane = tid & 63;
    const int wid = __builtin_amdgcn_readfirstlane(tid >> 6);
    const int s = lane;
    const float* w1b_p = w1b + (size_t)p * (CH * HIDN);
    const float* w3b_p = w3b + (size_t)p * (CH * HIDN * 3);
    float* outp = out + (size_t)bid * CH;

    for (int q = 0; q < 16; ++q) {
      const int c0 = wid * 64 + q * 4;
      float l1[4] = {0.f, 0.f, 0.f, 0.f};
      float l3[4] = {0.f, 0.f, 0.f, 0.f};

      for (int h4 = 0; h4 < HIDN; h4 += 4) {
        float h1v[4], h3a[4], h3b[4], h3c[4];
        #pragma unroll
        for (int u = 0; u < 4; ++u) {
          const int hh = h4 + u;
          h1v[u] = bf2f(h1_s[8 + hh * HROW + s]);
          h3a[u] = bf2f(h3_s[7 + hh * HROW + s]);
          h3b[u] = bf2f(h3_s[8 + hh * HROW + s]);
          h3c[u] = bf2f(h3_s[9 + hh * HROW + s]);
        }
        #pragma unroll
        for (int j = 0; j < 4; ++j) {
          const int c = c0 + j;
          const float4 wv  = *(const float4*)&w1b_p[c * HIDN + h4];
          const float* w3  = &w3b_p[(size_t)(c * HIDN + h4) * 3];
          const float4 w30 = *(const float4*)w3;
          const float4 w31 = *(const float4*)(w3 + 4);
          const float4 w32 = *(const float4*)(w3 + 8);
          float ww[12];
          ww[0]=w30.x; ww[1]=w30.y; ww[2]=w30.z; ww[3]=w30.w;
          ww[4]=w31.x; ww[5]=w31.y; ww[6]=w31.z; ww[7]=w31.w;
          ww[8]=w32.x; ww[9]=w32.y; ww[10]=w32.z; ww[11]=w32.w;
          l1[j] = fmaf(wv.x, h1v[0], fmaf(wv.y, h1v[1],
                  fmaf(wv.z, h1v[2], fmaf(wv.w, h1v[3], l1[j]))));
          #pragma unroll
          for (int u = 0; u < 4; ++u) {
            l3[j] = fmaf(ww[u * 3], h3a[u],
                    fmaf(ww[u * 3 + 1], h3b[u],
                    fmaf(ww[u * 3 + 2], h3c[u], l3[j])));
          }
        }
      }

      #pragma unroll
      for (int j = 0; j < 4; ++j) {
        const int c = c0 + j;
        const u16* xr = &x_s[8 + c * XROW];
        const float xm2 = bf2f(xr[s - 2]);
        const float xm1 = bf2f(xr[s - 1]);
        const float x0  = bf2f(xr[s]);
        const float xp1 = bf2f(xr[s + 1]);
        const float xp2 = bf2f(xr[s + 2]);
        const float NI = -INFINITY;
        const float mx3 = fmaxf(x0, fmaxf(s >= 1 ? xm1 : NI, s <= 62 ? xp1 : NI));
        const float mx5 = fmaxf(mx3, fmaxf(s >= 2 ? xm2 : NI, s <= 61 ? xp2 : NI));
        const float av3 = (xm1 + x0 + xp1) * (1.f / 3.f);
        const float av5 = (xm2 + xm1 + x0 + xp1 + xp2) * 0.2f;
        const float sg1 = 1.f / (1.f + __expf(-l1[j]));
        const float sg3 = 1.f / (1.f + __expf(-l3[j]));
        float feat = (av3 + mx3) * sg1 + (av5 + mx5) * sg3;
        #pragma unroll
        for (int off = 32; off >= 1; off >>= 1)
          feat = fmaxf(feat, __shfl_xor(feat, off));
        if (lane == 0) outp[c] = feat;
      }
    }
  }
}

extern "C" void kernel_launch(void* const* d_in, const int* in_sizes, int n_in,
                              void* d_out, int out_size, void* d_ws, size_t ws_size,
                              hipStream_t stream) {
  (void)in_sizes; (void)n_in; (void)out_size;
  const float* x   = (const float*)d_in[0];
  const float* w1a = (const float*)d_in[1];
  const float* w1b = (const float*)d_in[2];
  const float* w3a = (const float*)d_in[3];
  const float* w3b = (const float*)d_in[4];
  float* out = (float*)d_out;

  const size_t WS_NEED = 2621440ull * 2ull;  // 5 MB of bf16 weights
  if (ws_size >= WS_NEED) {
    u16* wsb = (u16*)d_ws;
    cvt_tap<<<1024, 256, 0, stream>>>(w1a, wsb,           3);  // W1A [p][t][h][c]
    cvt_tap<<<1024, 256, 0, stream>>>(w3a, wsb + 786432,  3);  // W3A [p][t][h][c]
    cvt_tap<<<1024, 256, 0, stream>>>(w1b, wsb + 1572864, 1);  // W1B [p][c][h]
    cvt_tap<<<1024, 256, 0, stream>>>(w3b, wsb + 1835008, 3);  // W3B [p][t][c][h]
    tfa_mfma<<<PARTS * NB, 256, 0, stream>>>(x, wsb, out);
  } else {
    tfa_kernel<<<PARTS * NB, 256, 0, stream>>>(x, w1a, w1b, w3a, w3b, out);
  }
}

// Round 3
// 128.068 us; speedup vs baseline: 8.6538x; 1.1169x over previous
//
#include <hip/hip_runtime.h>

#define PARTS 16
#define NB 128
#define CH 256
#define SL 64
#define HIDN 64

typedef unsigned short u16;
typedef unsigned short ushort8 __attribute__((ext_vector_type(8)));
typedef unsigned short ushort4v __attribute__((ext_vector_type(4)));
typedef __attribute__((ext_vector_type(8))) short short8v;
typedef __attribute__((ext_vector_type(4))) short short4v;
typedef __attribute__((ext_vector_type(4))) float f32x4;

__device__ __forceinline__ float bf2f(u16 u) {
  union { unsigned u; float f; } t; t.u = ((unsigned)u) << 16; return t.f;
}
__device__ __forceinline__ u16 f2bf(float f) {
  union { float f; unsigned u; } t; t.f = f;
  unsigned u = t.u;
  u += 0x7FFFu + ((u >> 16) & 1u);
  return (u16)(u >> 16);
}

// ===================== weight conversion prepass =====================
// out[p][t][x] = bf16(in[p][x][t]);  NX = 16384 fixed, NT = 3 or 1.
__global__ void cvt_tap(const float* __restrict__ in, u16* __restrict__ out, int NT) {
  const int i = blockIdx.x * 256 + threadIdx.x;   // p*16384 + x, exact grid
  const int p = i >> 14, xid = i & 16383;
  const float* src = in + (size_t)i * NT;
  for (int t = 0; t < NT; ++t)
    out[(size_t)(p * NT + t) * 16384 + xid] = f2bf(src[t]);
}

// ===================== MFMA main kernel =====================
// LDS layouts (bf16, XOR-swizzled in 16B chunks):
//  XT[r][c]: r = s+2, rows 0..67 (s=-2..65), 256 cols. pad rows 0,1,66,67 = 0.
//  HT[r][h]: r = s+1, rows 0..65 (s=-1..64), 64 cols.  pad rows 0,65 = 0.
#define XROWS 68
#define HROWS 66

__device__ __forceinline__ int xsw(int r, int c) { return (r * 256 + c) ^ ((r & 7) << 3); }
__device__ __forceinline__ int hsw(int r, int c) { return (r * 64 + c) ^ ((r & 7) << 3); }

// launch_bounds(256, 2): occupancy is LDS-bound at 3 blocks/CU (51.7 KB each),
// i.e. 3 waves/EU. waves-per-eu=2 keeps the VGPR cap at ~256 so the allocator
// does NOT spill to scratch chasing 6 waves/EU it can never reach (round-2:
// VGPR_Count=84=512/6 with ~100 MB of scratch write-back).
__global__ __launch_bounds__(256, 2) void tfa_mfma(
    const float* __restrict__ x,
    const u16* __restrict__ wsb,
    float* __restrict__ out)
{
  const u16* W1A = wsb;                 // [p][t][h][c]  786432
  const u16* W3A = wsb + 786432;        // [p][t][h][c]  786432
  const u16* W1B = wsb + 1572864;       // [p][c][h]     262144
  const u16* W3B = wsb + 1835008;       // [p][t][c][h]  786432

  __shared__ __attribute__((aligned(16))) u16 xt[XROWS * 256];   // 34816 B
  __shared__ __attribute__((aligned(16))) u16 ht1[HROWS * 64];   //  8448 B
  __shared__ __attribute__((aligned(16))) u16 ht3[HROWS * 64];   //  8448 B

  const int tid = threadIdx.x;
  const int bid = blockIdx.x;          // p*NB + n
  const int p = bid >> 7;
  const int lane = tid & 63;
  const int w = tid >> 6;              // wave id 0..3

  // ---- zero the pad rows ----
  if (tid < 128) {
    const int rr4 = (tid >> 5);
    const int r = (rr4 == 0) ? 0 : (rr4 == 1) ? 1 : (rr4 == 2) ? 66 : 67;
    const int c = (tid & 31) * 8;
    *(ushort8*)&xt[xsw(r, c)] = (ushort8)0;
  } else if (tid < 160) {
    const int t2 = tid - 128;          // 0..31: bit4=buffer, bit3=row, bits0-2=col chunk
    const int r = (t2 & 8) ? 65 : 0;
    const int c = (t2 & 7) * 8;
    u16* b = (t2 & 16) ? ht3 : ht1;
    *(ushort8*)&b[hsw(r, c)] = (ushort8)0;
  }

  // ---- stage x -> XT (transposed, bf16, swizzled) ----
  // lane = s; wave w covers c in [w*64, w*64+64); scalar loads coalesced across lanes
  {
    const float* xb = x + (size_t)bid * (CH * SL);
    const int s = lane;
    const int r = s + 2;
    #pragma unroll
    for (int j = 0; j < 8; ++j) {
      const int c0 = w * 64 + j * 8;
      ushort8 ov;
      #pragma unroll
      for (int k = 0; k < 8; ++k) ov[k] = f2bf(xb[(c0 + k) * 64 + s]);
      *(ushort8*)&xt[xsw(r, c0)] = ov;
    }
  }
  __syncthreads();

  // ---- phase A: conv1 both branches via MFMA, tap-GEMMs with shifted B rows ----
  // wave w owns h in [w*16, w*16+16); M=16h x N=64s x K=256c per tap
  {
    const int hm = lane & 15;          // A-frag m index
    const int kg = lane >> 4;          // k-group
    const int h = w * 16 + hm;
    f32x4 acc1[4], acc3[4];
    #pragma unroll
    for (int nt = 0; nt < 4; ++nt) { acc1[nt] = (f32x4)0.f; acc3[nt] = (f32x4)0.f; }

    #pragma unroll 2
    for (int ks = 0; ks < 8; ++ks) {
      const int kc = ks * 32 + kg * 8;
      short8v a1[3], a3[3];
      #pragma unroll
      for (int t = 0; t < 3; ++t) {
        a1[t] = *(const short8v*)&W1A[(size_t)((p * 3 + t) * 64 + h) * 256 + kc];
        a3[t] = *(const short8v*)&W3A[(size_t)((p * 3 + t) * 64 + h) * 256 + kc];
      }
      #pragma unroll
      for (int nt = 0; nt < 4; ++nt) {
        const int s = nt * 16 + hm;    // B-frag n index = lane&15
        #pragma unroll
        for (int t = 0; t < 3; ++t) {
          const int r = s + t + 1;     // s + (t-1) + 2
          const short8v b = *(const short8v*)&xt[xsw(r, kc)];
          acc1[nt] = __builtin_amdgcn_mfma_f32_16x16x32_bf16(a1[t], b, acc1[nt], 0, 0, 0);
          acc3[nt] = __builtin_amdgcn_mfma_f32_16x16x32_bf16(a3[t], b, acc3[nt], 0, 0, 0);
        }
      }
    }

    // epilogue: LeakyReLU -> bf16 -> HT[s][h] (D: col=lane&15 -> s, row=(lane>>4)*4+q -> h)
    const int hc = w * 16 + kg * 4;
    #pragma unroll
    for (int nt = 0; nt < 4; ++nt) {
      const int s = nt * 16 + hm;
      const int r = s + 1;
      ushort4v o1, o3;
      #pragma unroll
      for (int q = 0; q < 4; ++q) {
        float v1 = acc1[nt][q]; v1 = v1 >= 0.f ? v1 : 0.01f * v1;
        float v3 = acc3[nt][q]; v3 = v3 >= 0.f ? v3 : 0.01f * v3;
        o1[q] = f2bf(v1); o3[q] = f2bf(v3);
      }
      *(ushort4v*)&ht1[hsw(r, hc)] = o1;
      *(ushort4v*)&ht3[hsw(r, hc)] = o3;
    }
  }
  __syncthreads();

  // ---- phase B: conv2 both branches via MFMA + gates + pools + max over s ----
  // wave w owns c in [w*64, w*64+64). Processed in two mt-halves of 32 channels
  // each to halve peak register liveness (round-2 spilled ~190 B/thread).
  {
    const int cm = lane & 15;
    const int kg = lane >> 4;

    #pragma unroll
    for (int half = 0; half < 2; ++half) {
      const int mtb = half * 2;
      f32x4 acc[2][4];
      #pragma unroll
      for (int mt = 0; mt < 2; ++mt)
        #pragma unroll
        for (int nt = 0; nt < 4; ++nt) acc[mt][nt] = (f32x4)0.f;

      // branch 1: K=64h, k1 conv (no shift)
      #pragma unroll
      for (int ks = 0; ks < 2; ++ks) {
        const int kh = ks * 32 + kg * 8;
        short8v a[2];
        #pragma unroll
        for (int mt = 0; mt < 2; ++mt) {
          const int c = w * 64 + (mtb + mt) * 16 + cm;
          a[mt] = *(const short8v*)&W1B[((size_t)p * 256 + c) * 64 + kh];
        }
        #pragma unroll
        for (int nt = 0; nt < 4; ++nt) {
          const int s = nt * 16 + cm;
          const short8v b = *(const short8v*)&ht1[hsw(s + 1, kh)];
          #pragma unroll
          for (int mt = 0; mt < 2; ++mt)
            acc[mt][nt] = __builtin_amdgcn_mfma_f32_16x16x32_bf16(a[mt], b, acc[mt][nt], 0, 0, 0);
        }
      }

      // stash gates g1 = sigmoid(L1) as packed bf16 pairs (16 regs/half)
      unsigned g1p[2][4][2];
      #pragma unroll
      for (int mt = 0; mt < 2; ++mt)
        #pragma unroll
        for (int nt = 0; nt < 4; ++nt) {
          #pragma unroll
          for (int j = 0; j < 2; ++j) {
            const float ga = 1.f / (1.f + __expf(-acc[mt][nt][2 * j]));
            const float gb = 1.f / (1.f + __expf(-acc[mt][nt][2 * j + 1]));
            g1p[mt][nt][j] = (unsigned)f2bf(ga) | ((unsigned)f2bf(gb) << 16);
          }
          acc[mt][nt] = (f32x4)0.f;      // reuse for branch 3
        }

      // branch 3: 3 tap-GEMMs, K=64h each, B rows shifted
      #pragma unroll
      for (int ks = 0; ks < 2; ++ks) {
        const int kh = ks * 32 + kg * 8;
        #pragma unroll
        for (int t = 0; t < 3; ++t) {
          short8v a[2];
          #pragma unroll
          for (int mt = 0; mt < 2; ++mt) {
            const int c = w * 64 + (mtb + mt) * 16 + cm;
            a[mt] = *(const short8v*)&W3B[(size_t)((p * 3 + t) * 256 + c) * 64 + kh];
          }
          #pragma unroll
          for (int nt = 0; nt < 4; ++nt) {
            const int s = nt * 16 + cm;
            const short8v b = *(const short8v*)&ht3[hsw(s + t, kh)];  // s + (t-1) + 1
            #pragma unroll
            for (int mt = 0; mt < 2; ++mt)
              acc[mt][nt] = __builtin_amdgcn_mfma_f32_16x16x32_bf16(a[mt], b, acc[mt][nt], 0, 0, 0);
          }
        }
      }

      // epilogue: pools from XT, gates, fused max over s
      #pragma unroll
      for (int mt = 0; mt < 2; ++mt) {
        const int c4 = w * 64 + (mtb + mt) * 16 + kg * 4;   // D rows: 4 consecutive c
        float fmx0 = -INFINITY, fmx1 = -INFINITY, fmx2 = -INFINITY, fmx3 = -INFINITY;
        #pragma unroll
        for (int nt = 0; nt < 4; ++nt) {
          const int s = nt * 16 + cm;               // D col
          const ushort4v vm2 = *(const ushort4v*)&xt[xsw(s,     c4)];
          const ushort4v vm1 = *(const ushort4v*)&xt[xsw(s + 1, c4)];
          const ushort4v v0  = *(const ushort4v*)&xt[xsw(s + 2, c4)];
          const ushort4v vp1 = *(const ushort4v*)&xt[xsw(s + 3, c4)];
          const ushort4v vp2 = *(const ushort4v*)&xt[xsw(s + 4, c4)];
          const float NI = -INFINITY;
          float ft[4];
          #pragma unroll
          for (int q = 0; q < 4; ++q) {
            const float xm2 = bf2f(vm2[q]), xm1 = bf2f(vm1[q]), x0 = bf2f(v0[q]);
            const float xp1 = bf2f(vp1[q]), xp2 = bf2f(vp2[q]);
            const float mx3 = fmaxf(x0, fmaxf(s >= 1 ? xm1 : NI, s <= 62 ? xp1 : NI));
            const float mx5 = fmaxf(mx3, fmaxf(s >= 2 ? xm2 : NI, s <= 61 ? xp2 : NI));
            const float av3 = (xm1 + x0 + xp1) * (1.f / 3.f);
            const float av5 = (xm2 + xm1 + x0 + xp1 + xp2) * 0.2f;
            const float g1 = bf2f((u16)(g1p[mt][nt][q >> 1] >> ((q & 1) * 16)));
            const float g3 = 1.f / (1.f + __expf(-acc[mt][nt][q]));
            ft[q] = (av3 + mx3) * g1 + (av5 + mx5) * g3;
          }
          fmx0 = fmaxf(fmx0, ft[0]); fmx1 = fmaxf(fmx1, ft[1]);
          fmx2 = fmaxf(fmx2, ft[2]); fmx3 = fmaxf(fmx3, ft[3]);
        }
        // reduce max across the 16 lanes of each row-group (xor bits 0..3)
        #pragma unroll
        for (int off = 1; off < 16; off <<= 1) {
          fmx0 = fmaxf(fmx0, __shfl_xor(fmx0, off));
          fmx1 = fmaxf(fmx1, __shfl_xor(fmx1, off));
          fmx2 = fmaxf(fmx2, __shfl_xor(fmx2, off));
          fmx3 = fmaxf(fmx3, __shfl_xor(fmx3, off));
        }
        if (cm == 0) {
          float4 o; o.x = fmx0; o.y = fmx1; o.z = fmx2; o.w = fmx3;
          *(float4*)&out[(size_t)bid * 256 + c4] = o;
        }
      }
    }
  }
}

// ===================== fallback vector kernel (round-1, correct) =====================
#define XROW 72
#define HROW 72

__global__ __launch_bounds__(256, 2) void tfa_kernel(
    const float* __restrict__ x,
    const float* __restrict__ w1a,
    const float* __restrict__ w1b,
    const float* __restrict__ w3a,
    const float* __restrict__ w3b,
    float* __restrict__ out)
{
  __shared__ __attribute__((aligned(16))) u16 x_s[8 + CH * XROW];
  __shared__ __attribute__((aligned(16))) u16 h1_s[8 + HIDN * HROW];
  __shared__ __attribute__((aligned(16))) u16 h3_s[8 + HIDN * HROW];

  const int tid = threadIdx.x;
  const int bid = blockIdx.x;
  const int p = bid >> 7;

  {
    const ushort8 z = {0, 0, 0, 0, 0, 0, 0, 0};
    for (int i = tid; i < 257; i += 256) {
      u16* dst = (i == 0) ? &x_s[0] : &x_s[8 + (i - 1) * XROW + 64];
      *(ushort8*)dst = z;
    }
    if (tid < 65) {
      u16* d1 = (tid == 0) ? &h1_s[0] : &h1_s[8 + (tid - 1) * HROW + 64];
      *(ushort8*)d1 = z;
      u16* d3 = (tid == 0) ? &h3_s[0] : &h3_s[8 + (tid - 1) * HROW + 64];
      *(ushort8*)d3 = z;
    }
  }

  const float* xblk = x + (size_t)bid * (CH * SL);
  #pragma unroll
  for (int j = 0; j < 16; ++j) {
    const int g = tid + 256 * j;
    const float4 v = ((const float4*)xblk)[g];
    const int c = g >> 4, s4 = g & 15;
    ushort4v o;
    o[0] = f2bf(v.x); o[1] = f2bf(v.y); o[2] = f2bf(v.z); o[3] = f2bf(v.w);
    *(ushort4v*)&x_s[8 + c * XROW + s4 * 4] = o;
  }
  __syncthreads();

  {
    const int h = tid >> 2;
    const int sg = tid & 3;
    const int sb = sg << 4;
    float acc1[16], acc3[16];
    #pragma unroll
    for (int i = 0; i < 16; ++i) { acc1[i] = 0.f; acc3[i] = 0.f; }

    const float* w1a_p = w1a + ((size_t)p * HIDN + h) * (CH * 3);
    const float* w3a_p = w3a + ((size_t)p * HIDN + h) * (CH * 3);

    for (int c4 = 0; c4 < CH; c4 += 4) {
      const float4 a0v = *(const float4*)&w1a_p[c4 * 3];
      const float4 a1v = *(const float4*)&w1a_p[c4 * 3 + 4];
      const float4 a2v = *(const float4*)&w1a_p[c4 * 3 + 8];
      const float4 b0v = *(const float4*)&w3a_p[c4 * 3];
      const float4 b1v = *(const float4*)&w3a_p[c4 * 3 + 4];
      const float4 b2v = *(const float4*)&w3a_p[c4 * 3 + 8];
      float wa[12], wb[12];
      wa[0]=a0v.x; wa[1]=a0v.y; wa[2]=a0v.z; wa[3]=a0v.w;
      wa[4]=a1v.x; wa[5]=a1v.y; wa[6]=a1v.z; wa[7]=a1v.w;
      wa[8]=a2v.x; wa[9]=a2v.y; wa[10]=a2v.z; wa[11]=a2v.w;
      wb[0]=b0v.x; wb[1]=b0v.y; wb[2]=b0v.z; wb[3]=b0v.w;
      wb[4]=b1v.x; wb[5]=b1v.y; wb[6]=b1v.z; wb[7]=b1v.w;
      wb[8]=b2v.x; wb[9]=b2v.y; wb[10]=b2v.z; wb[11]=b2v.w;

      #pragma unroll
      for (int cc = 0; cc < 4; ++cc) {
        const int c = c4 + cc;
        const ushort8 w0v = *(const ushort8*)&x_s[c * XROW + sb];
        const ushort8 w1v = *(const ushort8*)&x_s[c * XROW + sb + 8];
        const ushort8 w2v = *(const ushort8*)&x_s[c * XROW + sb + 16];
        const ushort8 w3v = *(const ushort8*)&x_s[c * XROW + sb + 24];
        float xf[19];
        xf[0] = bf2f(w0v[7]);
        #pragma unroll
        for (int d = 0; d < 8; ++d) xf[1 + d] = bf2f(w1v[d]);
        #pragma unroll
        for (int d = 0; d < 8; ++d) xf[9 + d] = bf2f(w2v[d]);
        xf[17] = bf2f(w3v[0]);
        xf[18] = bf2f(w3v[1]);

        const float a0 = wa[cc * 3], a1 = wa[cc * 3 + 1], a2 = wa[cc * 3 + 2];
        const float b0 = wb[cc * 3], b1 = wb[cc * 3 + 1], b2 = wb[cc * 3 + 2];
        #pragma unroll
        for (int i = 0; i < 16; ++i) {
          const float xm = xf[i], x0 = xf[i + 1], xp = xf[i + 2];
          acc1[i] = fmaf(a0, xm, fmaf(a1, x0, fmaf(a2, xp, acc1[i])));
          acc3[i] = fmaf(b0, xm, fmaf(b1, x0, fmaf(b2, xp, acc3[i])));
        }
      }
    }

    ushort8 o1a, o1b, o3a, o3b;
    #pragma unroll
    for (int i = 0; i < 8; ++i) {
      float v1 = acc1[i];     v1 = v1 >= 0.f ? v1 : 0.01f * v1;
      float v3 = acc3[i];     v3 = v3 >= 0.f ? v3 : 0.01f * v3;
      o1a[i] = f2bf(v1); o3a[i] = f2bf(v3);
      float u1 = acc1[i + 8]; u1 = u1 >= 0.f ? u1 : 0.01f * u1;
      float u3 = acc3[i + 8]; u3 = u3 >= 0.f ? u3 : 0.01f * u3;
      o1b[i] = f2bf(u1); o3b[i] = f2bf(u3);
    }
    *(ushort8*)&h1_s[8 + h * HROW + sb]     = o1a;
    *(ushort8*)&h1_s[8 + h * HROW + sb + 8] = o1b;
    *(ushort8*)&h3_s[8 + h * HROW + sb]     = o3a;
    *(ushort8*)&h3_s[8 + h * HROW + sb + 8] = o3b;
  }
  __syncthreads();

  {
    const int lane = tid & 63;
    const int wid = __builtin_amdgcn_readfirstlane(tid >> 6);
    const int s = lane;
    const float* w1b_p = w1b + (size_t)p * (CH * HIDN);
    const float* w3b_p = w3b + (size_t)p * (CH * HIDN * 3);
    float* outp = out + (size_t)bid * CH;

    for (int q = 0; q < 16; ++q) {
      const int c0 = wid * 64 + q * 4;
      float l1[4] = {0.f, 0.f, 0.f, 0.f};
      float l3[4] = {0.f, 0.f, 0.f, 0.f};

      for (int h4 = 0; h4 < HIDN; h4 += 4) {
        float h1v[4], h3a[4], h3b[4], h3c[4];
        #pragma unroll
        for (int u = 0; u < 4; ++u) {
          const int hh = h4 + u;
          h1v[u] = bf2f(h1_s[8 + hh * HROW + s]);
          h3a[u] = bf2f(h3_s[7 + hh * HROW + s]);
          h3b[u] = bf2f(h3_s[8 + hh * HROW + s]);
          h3c[u] = bf2f(h3_s[9 + hh * HROW + s]);
        }
        #pragma unroll
        for (int j = 0; j < 4; ++j) {
          const int c = c0 + j;
          const float4 wv  = *(const float4*)&w1b_p[c * HIDN + h4];
          const float* w3  = &w3b_p[(size_t)(c * HIDN + h4) * 3];
          const float4 w30 = *(const float4*)w3;
          const float4 w31 = *(const float4*)(w3 + 4);
          const float4 w32 = *(const float4*)(w3 + 8);
          float ww[12];
          ww[0]=w30.x; ww[1]=w30.y; ww[2]=w30.z; ww[3]=w30.w;
          ww[4]=w31.x; ww[5]=w31.y; ww[6]=w31.z; ww[7]=w31.w;
          ww[8]=w32.x; ww[9]=w32.y; ww[10]=w32.z; ww[11]=w32.w;
          l1[j] = fmaf(wv.x, h1v[0], fmaf(wv.y, h1v[1],
                  fmaf(wv.z, h1v[2], fmaf(wv.w, h1v[3], l1[j]))));
          #pragma unroll
          for (int u = 0; u < 4; ++u) {
            l3[j] = fmaf(ww[u * 3], h3a[u],
                    fmaf(ww[u * 3 + 1], h3b[u],
                    fmaf(ww[u * 3 + 2], h3c[u], l3[j])));
          }
        }
      }

      #pragma unroll
      for (int j = 0; j < 4; ++j) {
        const int c = c0 + j;
        const u16* xr = &x_s[8 + c * XROW];
        const float xm2 = bf2f(xr[s - 2]);
        const float xm1 = bf2f(xr[s - 1]);
        const float x0  = bf2f(xr[s]);
        const float xp1 = bf2f(xr[s + 1]);
        const float xp2 = bf2f(xr[s + 2]);
        const float NI = -INFINITY;
        const float mx3 = fmaxf(x0, fmaxf(s >= 1 ? xm1 : NI, s <= 62 ? xp1 : NI));
        const float mx5 = fmaxf(mx3, fmaxf(s >= 2 ? xm2 : NI, s <= 61 ? xp2 : NI));
        const float av3 = (xm1 + x0 + xp1) * (1.f / 3.f);
        const float av5 = (xm2 + xm1 + x0 + xp1 + xp2) * 0.2f;
        const float sg1 = 1.f / (1.f + __expf(-l1[j]));
        const float sg3 = 1.f / (1.f + __expf(-l3[j]));
        float feat = (av3 + mx3) * sg1 + (av5 + mx5) * sg3;
        #pragma unroll
        for (int off = 32; off >= 1; off >>= 1)
          feat = fmaxf(feat, __shfl_xor(feat, off));
        if (lane == 0) outp[c] = feat;
      }
    }
  }
}

extern "C" void kernel_launch(void* const* d_in, const int* in_sizes, int n_in,
                              void* d_out, int out_size, void* d_ws, size_t ws_size,
                              hipStream_t stream) {
  (void)in_sizes; (void)n_in; (void)out_size;
  const float* x   = (const float*)d_in[0];
  const float* w1a = (const float*)d_in[1];
  const float* w1b = (const float*)d_in[2];
  const float* w3a = (const float*)d_in[3];
  const float* w3b = (const float*)d_in[4];
  float* out = (float*)d_out;

  const size_t WS_NEED = 2621440ull * 2ull;  // 5 MB of bf16 weights
  if (ws_size >= WS_NEED) {
    u16* wsb = (u16*)d_ws;
    cvt_tap<<<1024, 256, 0, stream>>>(w1a, wsb,           3);  // W1A [p][t][h][c]
    cvt_tap<<<1024, 256, 0, stream>>>(w3a, wsb + 786432,  3);  // W3A [p][t][h][c]
    cvt_tap<<<1024, 256, 0, stream>>>(w1b, wsb + 1572864, 1);  // W1B [p][c][h]
    cvt_tap<<<1024, 256, 0, stream>>>(w3b, wsb + 1835008, 3);  // W3B [p][t][c][h]
    tfa_mfma<<<PARTS * NB, 256, 0, stream>>>(x, wsb, out);
  } else {
    tfa_kernel<<<PARTS * NB, 256, 0, stream>>>(x, w1a, w1b, w3a, w3b, out);
  }
}